// Round 4
// baseline (193.576 us; speedup 1.0000x reference)
//
#include <hip/hip_runtime.h>
#include <math.h>

#define C_N 50000

typedef float f32x16 __attribute__((ext_vector_type(16)));
#define VZERO16 {0.f,0.f,0.f,0.f,0.f,0.f,0.f,0.f,0.f,0.f,0.f,0.f,0.f,0.f,0.f,0.f}

// ---- ws layout (float offsets, all multiples of 16) ----
#define OQ     0        // Q[1024]
#define OS     1024     // S[16]
#define OZ     1040     // z[2048]
#define OH     3088     // hbuf[1024]
#define OY     4112     // ybuf[1024]
#define OP     5136     // Pu[16][1024] UNnormalized pooled nodes
#define OSUMB  21520    // per-block head sums 1024*16
#define OQK    37904    // qk[1024][16]
#define OPP2   54288    // 2nd-level pool partials 64*16384
#define OPP    1102864  // pool partials nb*16384

__device__ __forceinline__ int brev4(int l){
  return ((l&1)<<3)|((l&2)<<1)|((l&4)>>1)|((l&8)>>3);
}

// Sum 16 values (in an f32x16) over all 64 lanes.
// Lanes l<16 end up holding the total for head brev4(l).
__device__ __forceinline__ float vred16(f32x16 v, int lane){
  float send, got;
#define RS(A,B,M) \
  send = (lane&M)? v[A] : v[B]; \
  got  = __shfl_xor(send, M);   \
  v[A] = ((lane&M)? v[B] : v[A]) + got;
  RS(0,8,1) RS(1,9,1) RS(2,10,1) RS(3,11,1)
  RS(4,12,1) RS(5,13,1) RS(6,14,1) RS(7,15,1)
  RS(0,4,2) RS(1,5,2) RS(2,6,2) RS(3,7,2)
  RS(0,2,4) RS(1,3,4)
  RS(0,1,8)
#undef RS
  float t = v[0];
  t += __shfl_xor(t,16);
  t += __shfl_xor(t,32);
  return t;
}

// ---- one-shot 16-output matvec block: out_j = sum_i x[i]*W[i*1024+j] ----
template<int IN>
__device__ __forceinline__ float mv_dot(const float* __restrict__ W,
    const float* __restrict__ x, int tid, int jblk){
  __shared__ float xs[IN];
  __shared__ float red[16][17];
  for (int k=tid;k<IN;k+=256) xs[k]=x[k];
  __syncthreads();
  int jq = tid&15, iq = tid>>4;
  int j = jblk*16 + jq;
  float acc = 0.f;
#pragma unroll 8
  for (int i=iq;i<IN;i+=16)
    acc = fmaf(xs[i], W[(size_t)i*1024 + j], acc);
  red[iq][jq] = acc;
  __syncthreads();
  float s = 0.f;
  if (tid < 16){
#pragma unroll
    for (int ii=0;ii<16;ii++) s += red[ii][tid];
  }
  return s;
}

// Q = z_prev@Wq + bq; also copy z_prev into z[1024:2048]
__global__ __launch_bounds__(256) void hm_mvQ(const float* __restrict__ W,
    const float* __restrict__ x, const float* __restrict__ bq,
    float* __restrict__ Q, float* __restrict__ z){
  float s = mv_dot<1024>(W, x, threadIdx.x, blockIdx.x);
  int tid = threadIdx.x;
  int j0 = blockIdx.x*16;
  if (tid < 16){
    Q[j0+tid] = s + bq[j0+tid];
    z[1024 + j0 + tid] = x[j0 + tid];
  }
}

// qk[i][h] = sum_t Wk[i][h*64+t] * Q[h*64+t]; one wave per row i.
__global__ __launch_bounds__(256) void hm_qk2(const float* __restrict__ Wk,
    const float* __restrict__ Q, float* __restrict__ qk){
  __shared__ float qlds[1024];
  int tid = threadIdx.x;
  for (int k=tid;k<1024;k+=256) qlds[k]=Q[k];
  __syncthreads();
  int w = tid>>6, l = tid&63;
  int i = blockIdx.x*4 + w;
  const float* wr = Wk + (size_t)i*1024 + l;
  f32x16 acc = VZERO16;
#define QKS(k) acc[k] = wr[k*64] * qlds[k*64 + l];
  QKS(0) QKS(1) QKS(2) QKS(3) QKS(4) QKS(5) QKS(6) QKS(7)
  QKS(8) QKS(9) QKS(10) QKS(11) QKS(12) QKS(13) QKS(14) QKS(15)
#undef QKS
  float t = vred16(acc, l);
  if (l < 16) qk[i*16 + brev4(l)] = t;
}

// Fused scores+softmax-exp+pool. Per 16-row batch:
//   phase1: score s[c][h] = nodes[c]·qk[:,h]  (cross-wave reduce in LDS)
//   phase2: e = exp(s/8) into LDS (no max shift: |s| small; Q·bk bias
//           is constant per head and cancels in softmax)
//   phase3: pool accs a[j][h] += nodes[c][j]*e[c][h] (rows re-read, L1/L2-hot)
// Emits per-block pool partials and per-block head sums (for S).
// grid=1024: 4 blocks/CU -> 4 waves/SIMD (VGPR 120 allows), hides the
// shfl-butterfly dependent chain that stalled the 512-block version.
__global__ __launch_bounds__(256) void hm_fused(const float* __restrict__ nodes,
    const float* __restrict__ qk, float* __restrict__ parts,
    float* __restrict__ sumpb){
  __shared__ float part[16][4][16];
  __shared__ float eb[16][16];
  const int tid = threadIdx.x, w = tid>>6, l = tid&63;
  const f32x16* qv = (const f32x16*)qk;
  const int i0 = w*256 + l*4;
  f32x16 q0 = qv[i0+0];
  f32x16 q1 = qv[i0+1];
  f32x16 q2 = qv[i0+2];
  f32x16 q3 = qv[i0+3];
  f32x16 a0 = VZERO16, a1 = VZERO16, a2 = VZERO16, a3 = VZERO16;
  float ssum = 0.f;
  const float4* n4 = (const float4*)nodes;
  const int r_ = tid>>4, h_ = tid&15;

  for (int cb = blockIdx.x; cb < 3125; cb += gridDim.x){
    size_t base = (size_t)cb*4096 + w*64 + l;
    float4 cur = n4[base];
#pragma unroll 4
    for (int r=0;r<16;r++){
      float4 nv = cur;
      if (r < 15) cur = n4[base + (size_t)(r+1)*256];
      f32x16 acc = q0*nv.x + q1*nv.y + q2*nv.z + q3*nv.w;
      float t = vred16(acc, l);
      if (l < 16) part[r][w][brev4(l)] = t;
    }
    __syncthreads();
    {
      float s = part[r_][0][h_]+part[r_][1][h_]+part[r_][2][h_]+part[r_][3][h_];
      eb[r_][h_] = __expf(s * 0.125f);
    }
    __syncthreads();
    if (tid < 16){
#pragma unroll
      for (int rr=0;rr<16;rr++) ssum += eb[rr][tid];
    }
#pragma unroll 4
    for (int r=0;r<16;r++){
      float4 nv = n4[base + (size_t)r*256];     // L1/L2 hit (just read)
      f32x16 u = *(const f32x16*)&eb[r][0];     // LDS broadcast
      a0 += u*nv.x; a1 += u*nv.y; a2 += u*nv.z; a3 += u*nv.w;
    }
    __syncthreads();
  }
  float* p = parts + (size_t)blockIdx.x*16384 + w*256 + l*4;
#pragma unroll
  for (int h=0;h<16;h++){
    float4 o = make_float4(a0[h],a1[h],a2[h],a3[h]);
    *(float4*)(p + h*1024) = o;
  }
  if (tid < 16) sumpb[blockIdx.x*16 + tid] = ssum;
}

// S[h] = sum over blocks of sumpb
__global__ __launch_bounds__(256) void hm_sumfin(const float* __restrict__ sumpb,
    float* __restrict__ S, int nb){
  __shared__ float red[16][17];
  int t = threadIdx.x, h = t&15, g = t>>4;
  float s = 0.f;
  for (int b=g; b<nb; b+=16) s += sumpb[b*16 + h];
  red[g][h] = s;
  __syncthreads();
  if (t < 16){
    float v = 0.f;
#pragma unroll
    for (int gg=0; gg<16; gg++) v += red[gg][t];
    S[t] = v;
  }
}

// Stage A: pp2[y][j] = sum of 16 partials (fully parallel, BW-bound)
__global__ __launch_bounds__(256) void hm_predA(const float* __restrict__ parts,
    float* __restrict__ pp2, int nb){
  int j = blockIdx.x*256 + threadIdx.x;
  int b0 = blockIdx.y*16;
  int b1 = b0+16 < nb ? b0+16 : nb;
  float s = 0.f;
  for (int b=b0;b<b1;b++) s += parts[(size_t)b*16384 + j];
  pp2[(size_t)blockIdx.y*16384 + j] = s;
}

// Stage B: Pu[j] = sum_y pp2[y][j]   (unnormalized; 1/S folded into mvV)
__global__ __launch_bounds__(256) void hm_predB(const float* __restrict__ pp2,
    float* __restrict__ Pu, int ny){
  int j = blockIdx.x*256 + threadIdx.x;
  float s = 0.f;
  for (int y=0;y<ny;y++) s += pp2[(size_t)y*16384 + j];
  Pu[j] = s;
}

// z[j] = (Pu[h]·Wv[:,j])/S[h] + bv[j], h = j>>6
__global__ __launch_bounds__(256) void hm_mvV(const float* __restrict__ W,
    const float* __restrict__ Pu, const float* __restrict__ S,
    const float* __restrict__ bv, float* __restrict__ z){
  const int hh = blockIdx.x>>2;
  const float* x = Pu + (size_t)hh*1024;
  float s = mv_dot<1024>(W, x, threadIdx.x, blockIdx.x);
  int tid = threadIdx.x;
  if (tid < 16){
    int j = blockIdx.x*16 + tid;
    z[j] = s / S[hh] + bv[j];
  }
}

__global__ __launch_bounds__(256) void hm_mvW1(const float* __restrict__ W,
    const float* __restrict__ z, const float* __restrict__ b1,
    float* __restrict__ hbuf){
  float s = mv_dot<2048>(W, z, threadIdx.x, blockIdx.x);
  int tid = threadIdx.x;
  if (tid < 16){
    int j = blockIdx.x*16 + tid;
    float v = s + b1[j];
    hbuf[j] = 0.5f * v * (1.0f + erff(v * 0.70710678118654752f));
  }
}

__global__ __launch_bounds__(256) void hm_mvW2(const float* __restrict__ W,
    const float* __restrict__ hb, const float* __restrict__ b2,
    float* __restrict__ y){
  float s = mv_dot<1024>(W, hb, threadIdx.x, blockIdx.x);
  int tid = threadIdx.x;
  if (tid < 16){
    int j = blockIdx.x*16 + tid;
    y[j] = s + b2[j];
  }
}

__global__ __launch_bounds__(256) void hm_rms(const float* __restrict__ y,
    const float* __restrict__ scale, float* __restrict__ out){
  __shared__ float red[4];
  __shared__ float msv;
  int tid = threadIdx.x;
  float local = 0.f;
  for (int j=tid;j<1024;j+=256){ float t = y[j]; local = fmaf(t,t,local); }
#pragma unroll
  for (int m=1;m<64;m<<=1) local += __shfl_xor(local, m);
  if ((tid&63)==0) red[tid>>6] = local;
  __syncthreads();
  if (tid==0){
    float s = red[0]+red[1]+red[2]+red[3];
    msv = rsqrtf(s*(1.0f/1024.0f) + 1e-6f);
  }
  __syncthreads();
  float r = msv;
  for (int j=tid;j<1024;j+=256) out[j] = scale[j]*y[j]*r;
}

extern "C" void kernel_launch(void* const* d_in, const int* in_sizes, int n_in,
                              void* d_out, int out_size, void* d_ws, size_t ws_size,
                              hipStream_t stream){
  const float* nodes  = (const float*)d_in[0];
  const float* z_prev = (const float*)d_in[1];
  const float* Wq = (const float*)d_in[2];
  const float* bq = (const float*)d_in[3];
  const float* Wk = (const float*)d_in[4];
  // d_in[5] = bk — cancels in softmax, unused
  const float* Wv = (const float*)d_in[6];
  const float* bv = (const float*)d_in[7];
  const float* W1 = (const float*)d_in[8];
  const float* b1 = (const float*)d_in[9];
  const float* W2 = (const float*)d_in[10];
  const float* b2 = (const float*)d_in[11];
  const float* scale = (const float*)d_in[12];
  float* ws  = (float*)d_ws;
  float* out = (float*)d_out;

  float* Qv   = ws + OQ;
  float* Sv   = ws + OS;
  float* z    = ws + OZ;
  float* hbuf = ws + OH;
  float* ybuf = ws + OY;
  float* Pu   = ws + OP;
  float* sumb = ws + OSUMB;
  float* qk   = ws + OQK;
  float* pp2  = ws + OPP2;
  float* pp   = ws + OPP;

  size_t wsf = ws_size/4;
  int nbp = 1;
  if (wsf > (size_t)(OPP + 16384)) nbp = (int)((wsf - OPP)/16384);
  if (nbp > 1024) nbp = 1024;
  if (nbp < 1) nbp = 1;
  int ny = (nbp + 15)/16;   // <= 64

  hm_mvQ   <<<64,  256, 0, stream>>>(Wq, z_prev, bq, Qv, z);
  hm_qk2   <<<256, 256, 0, stream>>>(Wk, Qv, qk);
  hm_fused <<<nbp, 256, 0, stream>>>(nodes, qk, pp, sumb);
  hm_sumfin<<<1,   256, 0, stream>>>(sumb, Sv, nbp);
  hm_predA <<<dim3(64,ny), 256, 0, stream>>>(pp, pp2, nbp);
  hm_predB <<<64,  256, 0, stream>>>(pp2, Pu, ny);
  hm_mvV   <<<64,  256, 0, stream>>>(Wv, Pu, Sv, bv, z);
  hm_mvW1  <<<64,  256, 0, stream>>>(W1, z, b1, hbuf);
  hm_mvW2  <<<64,  256, 0, stream>>>(W2, hbuf, b2, ybuf);
  hm_rms   <<<1,   256, 0, stream>>>(ybuf, scale, out);
}